// Round 9
// baseline (287.751 us; speedup 1.0000x reference)
//
#include <hip/hip_runtime.h>
#include <hip/hip_bf16.h>

// MultiHeadSelfAttention on MI355X (gfx950)
// Pipeline: [merged prep] -> fused QKV MFMA GEMM (R8: 128x192 tile, 6 waves,
// 80KB LDS -> 2 blocks/CU = 12 waves/CU (3/SIMD, m97 regime); same 32
// MFMA-per-barrier-per-wave as the proven 2-phase structure; grid 16x64 =
// 1024 blocks = exactly 2 rounds) -> MFMA flash attention vA (32x32x16,
// split-K qt>=8, glds staging, permlane32_swap, XCD swizzle) -> combine
// (ushort4) -> MFMA GEMM out-proj (proven 128x128 2-phase kernel).
// 8-phase template port abandoned: spec under-determined on the half-tile
// staging/read race (every phase reads all 4 live half-tiles; vmcnt(6)
// boundary leaves 3 in flight) — would be a third blind sync-structure
// gamble after R1/R6 refutations.

#define D_MODEL 1024
#define NHEADS  16
#define DK      64
#define BATCH   4
#define SEQ     2048
#define MROWS   (BATCH*SEQ)   // 8192

typedef short bvec8 __attribute__((ext_vector_type(8)));    // 8 bf16 = 4 VGPRs
typedef float fvec4  __attribute__((ext_vector_type(4)));   // 16x16 C/D frag
typedef float fvec16 __attribute__((ext_vector_type(16)));  // 32x32 C/D frag

__device__ __forceinline__ unsigned short f2bf(float f) {
    unsigned int x = __float_as_uint(f);
    x += 0x7fffu + ((x >> 16) & 1u);   // RNE
    return (unsigned short)(x >> 16);
}
__device__ __forceinline__ float bf2f(unsigned short u) {
    return __uint_as_float(((unsigned int)u) << 16);
}

__device__ __forceinline__ unsigned pack_bf16x2(float a, float b) {
#if __has_builtin(__builtin_amdgcn_cvt_pk_bf16_f32)
    typedef __bf16 bf16x2_t __attribute__((ext_vector_type(2)));
    union { bf16x2_t v; unsigned u; } cv;
    cv.v = __builtin_amdgcn_cvt_pk_bf16_f32(a, b);
    return cv.u;
#else
    return (unsigned)f2bf(a) | ((unsigned)f2bf(b) << 16);
#endif
}

__device__ __forceinline__ float fast_exp2(float x) {
#if __has_builtin(__builtin_amdgcn_exp2f)
    return __builtin_amdgcn_exp2f(x);      // single v_exp_f32
#else
    return exp2f(x);
#endif
}

// ---------------- merged prep kernel (one launch) ----------------
__global__ void prep_all_k(const float* __restrict__ x,
                           const float* __restrict__ wq, const float* __restrict__ wk,
                           const float* __restrict__ wv, const float* __restrict__ wo,
                           const float* __restrict__ bq, const float* __restrict__ bk,
                           const float* __restrict__ bv,
                           unsigned short* __restrict__ xb,
                           unsigned short* __restrict__ wqkvt,
                           unsigned short* __restrict__ wot,
                           float* __restrict__ cb) {
    const int bid = blockIdx.x;
    if (bid < 8192) {
        const int i = bid * 256 + threadIdx.x;   // n4 = 2,097,152 exactly
        float4 v = ((const float4*)x)[i];
        ushort4 o;
        o.x = f2bf(v.x); o.y = f2bf(v.y); o.z = f2bf(v.z); o.w = f2bf(v.w);
        ((ushort4*)xb)[i] = o;
    } else if (bid < 12288) {
        __shared__ float tile[32][33];
        const int bb = bid - 8192;
        const int z  = bb >> 10;                 // 0..3
        const int rem = bb & 1023;
        const int bx = rem & 31, by = rem >> 5;
        const float* W = (z == 0) ? wq : (z == 1) ? wk : (z == 2) ? wv : wo;
        unsigned short* Wt = (z == 3) ? wot : wqkvt + (size_t)z * D_MODEL * D_MODEL;
        const int n0 = bx * 32, k0 = by * 32;
        const int tx = threadIdx.x & 31;
        const int ty = (threadIdx.x >> 5) * 4;
#pragma unroll
        for (int i = 0; i < 4; ++i)
            tile[ty + i][tx] = W[(k0 + ty + i) * D_MODEL + n0 + tx];
        __syncthreads();
#pragma unroll
        for (int i = 0; i < 4; ++i)
            Wt[(n0 + ty + i) * D_MODEL + k0 + tx] = f2bf(tile[tx][ty + i]);
    } else {
        for (int i = threadIdx.x; i < 3072; i += 256) {
            float v = (i < 1024) ? bq[i] : (i < 2048) ? bk[i - 1024] : bv[i - 2048];
            cb[i] = v;
        }
    }
}

// -------- QKV GEMM: 128x192 tile, 6 waves, 2-phase dbuf glds --------------
// 2 blocks/CU (80KB LDS) -> 12 waves/CU. Same per-wave 64x64 output and 32
// MFMA/barrier as the proven kernel. Staging: 40 wave-issues (A:16, B:24)
// split 7/7/7/7/6/6; chunk c = idx*64+lane; LDS slot lane&7 of row
// idx*8+(lane>>3) holds global k-chunk (lane&7)^(lane>>3) (idx*8 = 0 mod 8,
// so the XOR is idx-invariant). Read side identical to the proven layout.
__global__ __launch_bounds__(384, 2)
void gemm_qkv192(const unsigned short* __restrict__ A,
                 const unsigned short* __restrict__ Bt,
                 const float* __restrict__ bias,
                 unsigned short* __restrict__ oq,
                 unsigned short* __restrict__ ok,
                 unsigned short* __restrict__ ov,
                 float qscale) {
    __shared__ __align__(16) unsigned short As[2][128 * 64];  // 32 KB
    __shared__ __align__(16) unsigned short Bs[2][192 * 64];  // 48 KB

    const int tid  = threadIdx.x;
    const int lane = tid & 63;
    const int w    = tid >> 6;            // 0..5
    const int wr   = (w >= 3) ? 1 : 0;    // 2 x 3 wave grid, 64x64 each
    const int wc   = w - wr * 3;
    const int quad = lane >> 4, l16 = lane & 15;

    // XCD swizzle (1024 blocks, %8==0)
    const unsigned nwg = gridDim.x * gridDim.y;
    unsigned f = blockIdx.y * gridDim.x + blockIdx.x;
    f = (f & 7) * (nwg >> 3) + (f >> 3);
    const int rowBlock = (int)(f / gridDim.x) * 128;
    const int colBlock = (int)(f % gridDim.x) * 192;

    const int lrow3 = lane >> 3;             // 0..7
    const int lswz  = (lane & 7) ^ lrow3;    // idx-invariant swizzled k-chunk

    const int nIss = (w < 4) ? 7 : 6;
    const int iss0 = (w < 4) ? w * 7 : 28 + (w - 4) * 6;

#define Q192_STAGE(KK, BUF) do {                                              \
    _Pragma("unroll")                                                         \
    for (int is = 0; is < 7; ++is) {                                          \
        if (is < nIss) {                                                      \
            const int idx = iss0 + is;                                        \
            if (idx < 16) {                                                   \
                const int grow = rowBlock + idx * 8 + lrow3;                  \
                __builtin_amdgcn_global_load_lds(                             \
                    (const __attribute__((address_space(1))) void*)           \
                        &A[(size_t)grow * D_MODEL + (KK) + lswz * 8],         \
                    (__attribute__((address_space(3))) void*)                 \
                        &As[BUF][idx * 512 + lane * 8], 16, 0, 0);            \
            } else {                                                          \
                const int bidx = idx - 16;                                    \
                const int grow = colBlock + bidx * 8 + lrow3;                 \
                __builtin_amdgcn_global_load_lds(                             \
                    (const __attribute__((address_space(1))) void*)           \
                        &Bt[(size_t)grow * D_MODEL + (KK) + lswz * 8],        \
                    (__attribute__((address_space(3))) void*)                 \
                        &Bs[BUF][bidx * 512 + lane * 8], 16, 0, 0);           \
            }                                                                 \
        }                                                                     \
    }                                                                         \
} while (0)

    fvec4 acc[4][4] = {};

    Q192_STAGE(0, 0);                         // prologue: tile 0 into buf 0

    for (int i = 0; i < 16; ++i) {            // K = 16 x 64
        __syncthreads();                      // drains vmcnt: tile i visible
        const int buf = i & 1;
        if (i < 15) Q192_STAGE((i + 1) * 64, buf ^ 1);
#pragma unroll
        for (int kc = 0; kc < 2; ++kc) {
            bvec8 af[4], bfr[4];
#pragma unroll
            for (int ii = 0; ii < 4; ++ii) {
                const int r = wr * 64 + ii * 16 + l16;
                af[ii] = *(const bvec8*)&As[buf][r * 64 + (((kc * 4 + quad) ^ (l16 & 7)) * 8)];
            }
#pragma unroll
            for (int j = 0; j < 4; ++j) {
                const int r = wc * 64 + j * 16 + l16;
                bfr[j] = *(const bvec8*)&Bs[buf][r * 64 + (((kc * 4 + quad) ^ (l16 & 7)) * 8)];
            }
#pragma unroll
            for (int ii = 0; ii < 4; ++ii)
#pragma unroll
                for (int j = 0; j < 4; ++j)
                    acc[ii][j] = __builtin_amdgcn_mfma_f32_16x16x32_bf16(
                        af[ii], bfr[j], acc[ii][j], 0, 0, 0);
        }
    }
#undef Q192_STAGE

    // epilogue: scatter Q,K (B,H,S,Dk) and V transposed (B,H,Dk,S)
#pragma unroll
    for (int i = 0; i < 4; ++i) {
#pragma unroll
        for (int j = 0; j < 4; ++j) {
            const int ncol = colBlock + wc * 64 + j * 16 + l16;
            const int which = ncol >> 10;      // uniform per (wc,j): 1024%16==0
            const int nn = ncol & 1023;
            const int h = nn >> 6, d = nn & 63;
            const float bv = bias[ncol];
            if (which == 2) {
                const int mrow0 = rowBlock + wr * 64 + i * 16 + quad * 4;
                const int b = mrow0 >> 11, s0 = mrow0 & (SEQ - 1);
                ushort4 pv;
                pv.x = f2bf(acc[i][j][0] + bv);
                pv.y = f2bf(acc[i][j][1] + bv);
                pv.z = f2bf(acc[i][j][2] + bv);
                pv.w = f2bf(acc[i][j][3] + bv);
                *(ushort4*)&ov[(((size_t)(b * NHEADS + h) * DK + d) * SEQ) + s0] = pv;
            } else {
#pragma unroll
                for (int r = 0; r < 4; ++r) {
                    const int mrow = rowBlock + wr * 64 + i * 16 + quad * 4 + r;
                    const int b = mrow >> 11, s = mrow & (SEQ - 1);
                    const float v = acc[i][j][r] + bv;
                    if (which == 0)
                        oq[(((b * NHEADS + h) * SEQ + s) * DK) + d] = f2bf(v * qscale);
                    else
                        ok[(((b * NHEADS + h) * SEQ + s) * DK) + d] = f2bf(v);
                }
            }
        }
    }
}

// ---------------- bf16 MFMA GEMM 128x128 2-phase (out-proj) ---------------
__global__ __launch_bounds__(256, 2)
void gemm_glds(const unsigned short* __restrict__ A,
               const unsigned short* __restrict__ Bt,
               const float* __restrict__ bias,
               float* __restrict__ of) {
    __shared__ __align__(16) unsigned short As[2][128 * 64];
    __shared__ __align__(16) unsigned short Bs[2][128 * 64];

    const int tid  = threadIdx.x;
    const int lane = tid & 63;
    const int w    = tid >> 6;
    const int wr   = w >> 1, wc = w & 1;     // 2x2 waves, 64x64 each
    const int quad = lane >> 4, l16 = lane & 15;

    const unsigned nwg = gridDim.x * gridDim.y;
    unsigned f = blockIdx.y * gridDim.x + blockIdx.x;
    f = (f & 7) * (nwg >> 3) + (f >> 3);
    const int rowBlock = (f / gridDim.x) * 128;
    const int colBlock = (f % gridDim.x) * 128;

    const int lrow   = lane >> 3;
    const int gchunk = (lane & 7) ^ lrow;

    fvec4 acc[4][4] = {};

    {   // prologue: issue tile 0 into buf 0
#pragma unroll
        for (int n = 0; n < 4; ++n) {
            const int g = w * 4 + n;
            __builtin_amdgcn_global_load_lds(
                (const __attribute__((address_space(1))) void*)
                    &A[(size_t)(rowBlock + g * 8 + lrow) * D_MODEL + gchunk * 8],
                (__attribute__((address_space(3))) void*)&As[0][g * 512], 16, 0, 0);
            __builtin_amdgcn_global_load_lds(
                (const __attribute__((address_space(1))) void*)
                    &Bt[(size_t)(colBlock + g * 8 + lrow) * D_MODEL + gchunk * 8],
                (__attribute__((address_space(3))) void*)&Bs[0][g * 512], 16, 0, 0);
        }
    }

    for (int i = 0; i < 16; ++i) {             // K = 16 x 64
        __syncthreads();
        const int buf = i & 1;
        if (i < 15) {
            const int k1 = (i + 1) * 64;
#pragma unroll
            for (int n = 0; n < 4; ++n) {
                const int g = w * 4 + n;
                __builtin_amdgcn_global_load_lds(
                    (const __attribute__((address_space(1))) void*)
                        &A[(size_t)(rowBlock + g * 8 + lrow) * D_MODEL + k1 + gchunk * 8],
                    (__attribute__((address_space(3))) void*)&As[buf ^ 1][g * 512], 16, 0, 0);
                __builtin_amdgcn_global_load_lds(
                    (const __attribute__((address_space(1))) void*)
                        &Bt[(size_t)(colBlock + g * 8 + lrow) * D_MODEL + k1 + gchunk * 8],
                    (__attribute__((address_space(3))) void*)&Bs[buf ^ 1][g * 512], 16, 0, 0);
            }
        }
#pragma unroll
        for (int kc = 0; kc < 2; ++kc) {
            bvec8 af[4], bfr[4];
#pragma unroll
            for (int ii = 0; ii < 4; ++ii) {
                int r = wr * 64 + ii * 16 + l16;
                af[ii] = *(const bvec8*)&As[buf][r * 64 + (((kc * 4 + quad) ^ (l16 & 7)) * 8)];
            }
#pragma unroll
            for (int j = 0; j < 4; ++j) {
                int r = wc * 64 + j * 16 + l16;
                bfr[j] = *(const bvec8*)&Bs[buf][r * 64 + (((kc * 4 + quad) ^ (l16 & 7)) * 8)];
            }
#pragma unroll
            for (int ii = 0; ii < 4; ++ii)
#pragma unroll
                for (int j = 0; j < 4; ++j)
                    acc[ii][j] = __builtin_amdgcn_mfma_f32_16x16x32_bf16(
                        af[ii], bfr[j], acc[ii][j], 0, 0, 0);
        }
    }

#pragma unroll
    for (int i = 0; i < 4; ++i) {
#pragma unroll
        for (int j = 0; j < 4; ++j) {
            int ncol = colBlock + wc * 64 + j * 16 + l16;
            float bv = bias[ncol];
#pragma unroll
            for (int r = 0; r < 4; ++r) {
                int mrow = rowBlock + wr * 64 + i * 16 + quad * 4 + r;
                of[(size_t)mrow * D_MODEL + ncol] = acc[i][j][r] + bv;
            }
        }
    }
}

// ---------------- MFMA flash attention vA (32x32x16, balanced split-K) -----
__global__ __launch_bounds__(256, 4)
void attn_mfmaA(const unsigned short* __restrict__ Q,   // (B,H,S,Dk) bf16, scaled
                const unsigned short* __restrict__ K,   // (B,H,S,Dk) bf16
                const unsigned short* __restrict__ Vt,  // (B,H,Dk,S) bf16
                unsigned short* __restrict__ O,         // (B,S,H*Dk) bf16
                unsigned short* __restrict__ Opart,     // [16][64][128][64] bf16
                float* __restrict__ Lpart) {            // [16][64][128] fp32
    __shared__ __align__(16) unsigned short Ksm[2][64 * 64];  // [key][dk] swizzled
    __shared__ __align__(16) unsigned short Vsm[2][64 * 64];  // [d][key] swizzled
    __shared__ float Lsh[4][32];

    const int tid  = threadIdx.x;
    const int lane = tid & 63;
    const int wq   = tid >> 6;
    const int hf   = lane >> 5;            // half-wave
    const int l32  = lane & 31;

    // XCD swizzle: logical f -> (bx, hh, b); XCD gets contiguous head-groups
    unsigned f = (blockIdx.z * 16 + blockIdx.y) * 24 + blockIdx.x;
    f = (f & 7) * 192 + (f >> 3);          // 1536/8 = 192
    const int bx = f % 24;
    const int hh = (f / 24) & 15;
    const int b  = f / 384;
    const int hb = b * NHEADS + hh;

    // work decode (heavy-first order; mode 2 = full, 0/1 = half)
    static const int qt_tbl[24] = {15,15,7,14,14,6,13,13,12,12,5,11,
                                   11,10,10,4,9,9,8,8,3,2,1,0};
    static const int md_tbl[24] = {0,1,2,0,1,2,0,1,0,1,2,0,
                                   1,0,1,2,0,1,0,1,2,2,2,2};
    const int qt = qt_tbl[bx];
    const int md = md_tbl[bx];
    const bool part = (md < 2);
    const int kt0 = (md == 1) ? qt + 1 : 0;
    const int kt1 = (md == 0) ? qt + 1 : 2 * qt + 2;
    const int slot = part ? ((qt - 8) * 2 + md) : 0;

    const size_t bhq = ((size_t)hb) * SEQ * DK;
    const unsigned short* Qb = Q + bhq;
    const unsigned short* Kb = K + bhq;
    const unsigned short* Vb = Vt + bhq;   // (Dk, S)

    const int q0 = qt * 128 + wq * 32;     // wave's first q row (global)

    // Q B-frags (32x32x16): B[k=dk=(hf*8+j)+kc*16][n=q=l32], kept in regs
    bvec8 qf[4];
#pragma unroll
    for (int kc = 0; kc < 4; ++kc)
        qf[kc] = *(const bvec8*)&Qb[(q0 + l32) * DK + kc * 16 + hf * 8];

    // glds staging: thread t owns 16B chunks t and t+256 of each 64x64 tile.
    // chunk c = row*8 + slot; slot holds global chunk slot^(row&7).
    const int r1 = tid >> 3;               // 0..31 (second row = r1+32, same &7)
    const int lcs = (tid & 7) ^ (r1 & 7);  // pre-swizzled global chunk index

#define ATTN_STAGE(KT, NB) do {                                               \
    const unsigned short* kg_ = Kb + ((KT) * 64 + r1) * DK + lcs * 8;         \
    const unsigned short* vg_ = Vb + (size_t)r1 * SEQ + (KT) * 64 + lcs * 8;  \
    __builtin_amdgcn_global_load_lds(                                         \
        (const __attribute__((address_space(1))) void*)kg_,                   \
        (__attribute__((address_space(3))) void*)&Ksm[NB][wq * 512], 16, 0, 0); \
    __builtin_amdgcn_global_load_lds(                                         \
        (const __attribute__((address_space(1))) void*)(kg_ + 32 * DK),       \
        (__attribute__((address_space(3))) void*)&Ksm[NB][2048 + wq * 512], 16, 0, 0); \
    __builtin_amdgcn_global_load_lds(                                         \
        (const __attribute__((address_space(1))) void*)vg_,                   \
        (__attribute__((address_space(3))) void*)&Vsm[NB][wq * 512], 16, 0, 0); \
    __builtin_amdgcn_global_load_lds(                                         \
        (const __attribute__((address_space(1))) void*)(vg_ + 32 * SEQ),      \
        (__attribute__((address_space(3))) void*)&Vsm[NB][2048 + wq * 512], 16, 0, 0); \
} while (0)

    const int ktact = 2 * qt + (wq >> 1);  // this wave's diagonal tile
    const int mofs  = (wq & 1) << 5;       // key offset for diagonal masking

    ATTN_STAGE(kt0, 0);                    // preload tile kt0 into buf 0

    fvec16 acc0 = {};                      // O[q=(r&3)+8*(r>>2)+4*hf][d=l32]
    fvec16 acc1 = {};                      // same, d=32+l32
    float lp = 0.f;                        // partial l for q=l32

    for (int kt = kt0; kt < kt1; ++kt) {
        __syncthreads();                   // drains vmcnt: tile kt visible;
                                           // buf^1 readers done (prev iter)
        const int buf = (kt - kt0) & 1;
        if (kt + 1 < kt1)                  // next tile in flight during compute
            ATTN_STAGE(kt + 1, buf ^ 1);
        if (kt <= ktact) {                 // wave-uniform: skip fully-masked tiles
            const unsigned short* Kbuf = &Ksm[buf][0];
            const unsigned short* Vbuf = &Vsm[buf][0];

            fvec16 s0 = {}, s1 = {};
            __builtin_amdgcn_s_setprio(1);     // T5: favor MFMA-issuing wave
#pragma unroll
            for (int kc = 0; kc < 4; ++kc) {
                const int ch = (((kc * 2 + hf) ^ (l32 & 7)) * 8);
                bvec8 a0 = *(const bvec8*)&Kbuf[l32 * 64 + ch];
                bvec8 a1 = *(const bvec8*)&Kbuf[(32 + l32) * 64 + ch];
                s0 = __builtin_amdgcn_mfma_f32_32x32x16_bf16(a0, qf[kc], s0, 0, 0, 0);
                s1 = __builtin_amdgcn_mfma_f32_32x32x16_bf16(a1, qf[kc], s1, 0, 0, 0);
            }
            __builtin_amdgcn_s_setprio(0);

            if (kt == ktact) {             // diagonal tile: mask key > q
#pragma unroll
                for (int r = 0; r < 16; ++r) {
                    const int key0 = (r & 3) + 8 * (r >> 2) + 4 * hf - mofs;
                    if (key0 > l32)      s0[r] = -__builtin_inff();
                    if (key0 + 32 > l32) s1[r] = -__builtin_inff();
                }
            }

            unsigned pk[16];
#pragma unroll
            for (int m = 0; m < 8; ++m) {
                float p0 = fast_exp2(s0[2 * m]);
                float p1 = fast_exp2(s0[2 * m + 1]);
                float p2 = fast_exp2(s1[2 * m]);
                float p3 = fast_exp2(s1[2 * m + 1]);
                lp += (p0 + p1) + (p2 + p3);
                pk[m]     = pack_bf16x2(p0, p1);
                pk[8 + m] = pack_bf16x2(p2, p3);
            }

            __builtin_amdgcn_s_setprio(1);     // T5: PV MFMA cluster
#pragma unroll
            for (int kc16 = 0; kc16 < 4; ++kc16) {
                const int b0 = (kc16 >> 1) * 8 + (kc16 & 1) * 4;
                union { unsigned u[4]; bvec8 v; } afu;
#if __has_builtin(__builtin_amdgcn_permlane32_swap)
                {
                    auto r02 = __builtin_amdgcn_permlane32_swap(
                        pk[b0 + 0], pk[b0 + 2], false, false);
                    auto r13 = __builtin_amdgcn_permlane32_swap(
                        pk[b0 + 1], pk[b0 + 3], false, false);
                    unsigned o02[2], o13[2];
                    __builtin_memcpy(o02, &r02, 8);
                    __builtin_memcpy(o13, &r13, 8);
                    afu.u[0] = o02[0]; afu.u[2] = o02[1];
                    afu.u[1] = o13[0]; afu.u[3] = o13[1];
                }
#else
                {
                    unsigned sw0 = __shfl_xor(pk[b0 + 0], 32);
                    unsigned sw1 = __shfl_xor(pk[b0 + 1], 32);
                    unsigned sw2 = __shfl_xor(pk[b0 + 2], 32);
                    unsigned sw3 = __shfl_xor(pk[b0 + 3], 32);
                    afu.u[0] = hf ? sw2 : pk[b0 + 0];
                    afu.u[1] = hf ? sw3 : pk[b0 + 1];
                    afu.u[2] = hf ? pk[b0 + 2] : sw0;
                    afu.u[3] = hf ? pk[b0 + 3] : sw1;
                }
#endif
                const int ch = (((kc16 * 2 + hf) ^ (l32 & 7)) * 8);
                bvec8 bv0 = *(const bvec8*)&Vbuf[l32 * 64 + ch];
                bvec8 bv1 = *(const bvec8*)&Vbuf[(32 + l32) * 64 + ch];
                acc0 = __builtin_amdgcn_mfma_f32_32x32x16_bf16(afu.v, bv0, acc0, 0, 0, 0);
                acc1 = __builtin_amdgcn_mfma_f32_32x32x16_bf16(afu.v, bv1, acc1, 0, 0, 0);
            }
            __builtin_amdgcn_s_setprio(0);
        }
    }
#undef ATTN_STAGE

    const float l = lp + __shfl_xor(lp, 32);   // l(q=l32), replicated per half

    if (part) {
        if (lane < 32)
            Lpart[((size_t)slot * 64 + hb) * 128 + wq * 32 + l32] = l;
        unsigned short* Od = Opart + (((size_t)slot * 64 + hb) * 128 + wq * 32) * 64;
#pragma unroll
        for (int g = 0; g < 4; ++g)
#pragma unroll
            for (int rr = 0; rr < 4; ++rr) {
                const int reg = g * 4 + rr;
                const int qrl = g * 8 + 4 * hf + rr;
                Od[(size_t)qrl * 64 + l32]      = f2bf(acc0[reg]);
                Od[(size_t)qrl * 64 + 32 + l32] = f2bf(acc1[reg]);
            }
    } else {
        if (lane < 32) Lsh[wq][l32] = l;   // same-wave LDS dep (lgkmcnt)
#pragma unroll
        for (int g = 0; g < 4; ++g) {
            float4 lv = *(const float4*)&Lsh[wq][g * 8 + 4 * hf];
#pragma unroll
            for (int rr = 0; rr < 4; ++rr) {
                const int reg = g * 4 + rr;
                const int qrow = q0 + g * 8 + 4 * hf + rr;
                const float inv = 1.f / ((const float*)&lv)[rr];
                unsigned short* dst = O + (size_t)(b * SEQ + qrow) * D_MODEL + hh * DK + l32;
                dst[0]  = f2bf(acc0[reg] * inv);
                dst[32] = f2bf(acc1[reg] * inv);
            }
        }
    }
}

// combine the two key-chunks for qt in [8,16): O = (Oa+Ob)/(la+lb) -> bf16
__global__ void attn_combine_k(const unsigned short* __restrict__ Opart,
                               const float* __restrict__ Lpart,
                               unsigned short* __restrict__ O) {
    const int qt = 8 + blockIdx.x;
    const int h = blockIdx.y, b = blockIdx.z;
    const int hb = b * NHEADS + h;
    const int s0 = (qt - 8) * 2;
    const unsigned short* A  = Opart + ((size_t)(s0)*64 + hb) * 128 * 64;
    const unsigned short* Bp = Opart + ((size_t)(s0 + 1) * 64 + hb) * 128 * 64;
    const float* LA = Lpart + ((size_t)(s0)*64 + hb) * 128;
    const float* LB = Lpart + ((size_t)(s0 + 1) * 64 + hb) * 128;
    for (int e4 = threadIdx.x; e4 < 2048; e4 += 256) {
        const int qr = e4 >> 4, d4 = (e4 & 15) * 4;
        const float inv = 1.f / (LA[qr] + LB[qr]);
        ushort4 a = *(const ushort4*)&A[(size_t)qr * 64 + d4];
        ushort4 p = *(const ushort4*)&Bp[(size_t)qr * 64 + d4];
        ushort4 o;
        o.x = f2bf((bf2f(a.x) + bf2f(p.x)) * inv);
        o.y = f2bf((bf2f(a.y) + bf2f(p.y)) * inv);
        o.z = f2bf((bf2f(a.z) + bf2f(p.z)) * inv);
        o.w = f2bf((bf2f(a.w) + bf2f(p.w)) * inv);
        *(ushort4*)&O[(size_t)(b * SEQ + qt * 128 + qr) * D_MODEL + h * DK + d4] = o;
    }
}

// ---------------- launch ----------------

extern "C" void kernel_launch(void* const* d_in, const int* in_sizes, int n_in,
                              void* d_out, int out_size, void* d_ws, size_t ws_size,
                              hipStream_t stream) {
    const float* x  = (const float*)d_in[0];
    const float* wq = (const float*)d_in[1];
    const float* bq = (const float*)d_in[2];
    const float* wk = (const float*)d_in[3];
    const float* bk = (const float*)d_in[4];
    const float* wv = (const float*)d_in[5];
    const float* bv = (const float*)d_in[6];
    const float* wo = (const float*)d_in[7];
    const float* bo = (const float*)d_in[8];
    float* out = (float*)d_out;

    char* ws = (char*)d_ws;
    const size_t MB = 1u << 20;
    unsigned short* xb    = (unsigned short*)(ws);            // 16 MB  x bf16
    unsigned short* wqkvt = (unsigned short*)(ws + 16 * MB);  //  6 MB  [Wq;Wk;Wv]^T
    unsigned short* wot   = (unsigned short*)(ws + 22 * MB);  //  2 MB (live thru out-proj)
    unsigned short* qb    = (unsigned short*)(ws + 24 * MB);  // 16 MB each
    unsigned short* kb    = (unsigned short*)(ws + 40 * MB);
    unsigned short* vtb   = (unsigned short*)(ws + 56 * MB);  // V^T (B,H,Dk,S)
    unsigned short* ab    = (unsigned short*)(ws + 72 * MB);  // attn out, ends 88 MB
    float* cbias = (float*)(ws + 72 * MB);  // 12 KB, consumed by QKV GEMM
    // split-K partials overlay xb/wqkvt (dead after the QKV GEMM):
    unsigned short* Opart = (unsigned short*)(ws);  // 16 MB [16][64][128][64] bf16
    float* Lpart = (float*)(ws + 16 * MB);          // 512 KB [16][64][128] fp32

    // merged prep: convert (8192 blocks) | transpose (4096) | cbias (1)
    prep_all_k<<<12289, 256, 0, stream>>>(x, wq, wk, wv, wo, bq, bk, bv,
                                          xb, wqkvt, wot, cbias);

    // Q pre-scale folds softmax's 1/sqrt(Dk) AND log2(e) for exp2-domain softmax
    const float QSCALE = 0.125f * 1.44269504088896340736f;

    // fused QKV projection: N = 3072, 128x192 tiles, 1024 blocks
    gemm_qkv192<<<dim3(3072 / 192, MROWS / 128), 384, 0, stream>>>(
        xb, wqkvt, cbias, qb, kb, vtb, QSCALE);

    attn_mfmaA<<<dim3(24, NHEADS, BATCH), 256, 0, stream>>>(
        qb, kb, vtb, ab, Opart, Lpart);
    attn_combine_k<<<dim3(8, NHEADS, BATCH), 256, 0, stream>>>(Opart, Lpart, ab);

    // out projection: fp32 output + bias
    gemm_glds<<<dim3(D_MODEL / 128, MROWS / 128), 256, 0, stream>>>(
        ab, wot, bo, out);
}

// Round 10
// 263.133 us; speedup vs baseline: 1.0936x; 1.0936x over previous
//
#include <hip/hip_runtime.h>
#include <hip/hip_bf16.h>

// MultiHeadSelfAttention on MI355X (gfx950)
// Pipeline: [merged prep] -> fused QKV MFMA GEMM (2-phase 128x128 BK=64 dbuf
// glds — FROZEN: R1/R4/R6/R8 structure perturbations all refuted) -> MFMA
// flash attention vA (32x32x16, split-K qt>=8, glds staging, permlane32_swap,
// XCD swizzle) -> combine (ushort4) -> MFMA GEMM out-proj.
// R9: revert to R7-exact pipeline + operand-swap epilogue for Q/K blocks:
//     QKV blocks are column-pure (bx 0-7=Q, 8-15=K, 16-23=V), so Q/K blocks
//     compute mfma(Wfrag, Xfrag) -> transposed C layout (lane's 4 regs = 4
//     consecutive d) -> 16 ushort4 stores instead of 64 scalar ushort.
//     V blocks keep original order (4 consecutive s -> existing V^T pack).
//     Compute loop differs only by wave-uniform operand-role selects.

#define D_MODEL 1024
#define NHEADS  16
#define DK      64
#define BATCH   4
#define SEQ     2048
#define MROWS   (BATCH*SEQ)   // 8192

typedef short bvec8 __attribute__((ext_vector_type(8)));    // 8 bf16 = 4 VGPRs
typedef float fvec4  __attribute__((ext_vector_type(4)));   // 16x16 C/D frag
typedef float fvec16 __attribute__((ext_vector_type(16)));  // 32x32 C/D frag

__device__ __forceinline__ unsigned short f2bf(float f) {
    unsigned int x = __float_as_uint(f);
    x += 0x7fffu + ((x >> 16) & 1u);   // RNE
    return (unsigned short)(x >> 16);
}
__device__ __forceinline__ float bf2f(unsigned short u) {
    return __uint_as_float(((unsigned int)u) << 16);
}

__device__ __forceinline__ unsigned pack_bf16x2(float a, float b) {
#if __has_builtin(__builtin_amdgcn_cvt_pk_bf16_f32)
    typedef __bf16 bf16x2_t __attribute__((ext_vector_type(2)));
    union { bf16x2_t v; unsigned u; } cv;
    cv.v = __builtin_amdgcn_cvt_pk_bf16_f32(a, b);
    return cv.u;
#else
    return (unsigned)f2bf(a) | ((unsigned)f2bf(b) << 16);
#endif
}

__device__ __forceinline__ float fast_exp2(float x) {
#if __has_builtin(__builtin_amdgcn_exp2f)
    return __builtin_amdgcn_exp2f(x);      // single v_exp_f32
#else
    return exp2f(x);
#endif
}

// ---------------- merged prep kernel (one launch) ----------------
__global__ void prep_all_k(const float* __restrict__ x,
                           const float* __restrict__ wq, const float* __restrict__ wk,
                           const float* __restrict__ wv, const float* __restrict__ wo,
                           const float* __restrict__ bq, const float* __restrict__ bk,
                           const float* __restrict__ bv,
                           unsigned short* __restrict__ xb,
                           unsigned short* __restrict__ wqkvt,
                           unsigned short* __restrict__ wot,
                           float* __restrict__ cb) {
    const int bid = blockIdx.x;
    if (bid < 8192) {
        const int i = bid * 256 + threadIdx.x;   // n4 = 2,097,152 exactly
        float4 v = ((const float4*)x)[i];
        ushort4 o;
        o.x = f2bf(v.x); o.y = f2bf(v.y); o.z = f2bf(v.z); o.w = f2bf(v.w);
        ((ushort4*)xb)[i] = o;
    } else if (bid < 12288) {
        __shared__ float tile[32][33];
        const int bb = bid - 8192;
        const int z  = bb >> 10;                 // 0..3
        const int rem = bb & 1023;
        const int bx = rem & 31, by = rem >> 5;
        const float* W = (z == 0) ? wq : (z == 1) ? wk : (z == 2) ? wv : wo;
        unsigned short* Wt = (z == 3) ? wot : wqkvt + (size_t)z * D_MODEL * D_MODEL;
        const int n0 = bx * 32, k0 = by * 32;
        const int tx = threadIdx.x & 31;
        const int ty = (threadIdx.x >> 5) * 4;
#pragma unroll
        for (int i = 0; i < 4; ++i)
            tile[ty + i][tx] = W[(k0 + ty + i) * D_MODEL + n0 + tx];
        __syncthreads();
#pragma unroll
        for (int i = 0; i < 4; ++i)
            Wt[(n0 + ty + i) * D_MODEL + k0 + tx] = f2bf(tile[tx][ty + i]);
    } else {
        for (int i = threadIdx.x; i < 3072; i += 256) {
            float v = (i < 1024) ? bq[i] : (i < 2048) ? bk[i - 1024] : bv[i - 2048];
            cb[i] = v;
        }
    }
}

// ---------------- bf16 MFMA GEMM, dbuf global_load_lds ----------------
// T1 XCD swizzle (grids 1536 and 512, both %8==0). 2-phase structure FROZEN.
// swp (Q/K blocks): operand roles exchanged -> C^T layout, d-contiguous regs.
__global__ __launch_bounds__(256, 2)
void gemm_glds(const unsigned short* __restrict__ A,
               const unsigned short* __restrict__ Bt,
               const float* __restrict__ bias,
               unsigned short* __restrict__ oq,
               unsigned short* __restrict__ ok,
               unsigned short* __restrict__ ov,
               float* __restrict__ of,
               float qscale, int mode) {
    __shared__ __align__(16) unsigned short As[2][128 * 64];
    __shared__ __align__(16) unsigned short Bs[2][128 * 64];

    const int tid  = threadIdx.x;
    const int lane = tid & 63;
    const int w    = tid >> 6;
    const int wr   = w >> 1, wc = w & 1;     // 2x2 waves, 64x64 each
    const int quad = lane >> 4, l16 = lane & 15;

    // XCD swizzle: hardware id h -> logical chunk (h&7)*cpx + h>>3
    const unsigned nwg = gridDim.x * gridDim.y;
    unsigned f = blockIdx.y * gridDim.x + blockIdx.x;
    f = (f & 7) * (nwg >> 3) + (f >> 3);
    const int rowBlock = (f / gridDim.x) * 128;
    const int colBlock = (f % gridDim.x) * 128;

    // Q/K blocks (column-pure): swap operand roles for d-contiguous epilogue
    const bool swp = (mode == 0) && (colBlock < 2048);
    const int rba = (swp ? wc : wr) * 64;    // row base for first operand
    const int rbb = (swp ? wr : wc) * 64;    // row base for second operand

    const int lrow   = lane >> 3;
    const int gchunk = (lane & 7) ^ lrow;

    fvec4 acc[4][4] = {};

    {   // prologue: issue tile 0 into buf 0
#pragma unroll
        for (int n = 0; n < 4; ++n) {
            const int g = w * 4 + n;
            __builtin_amdgcn_global_load_lds(
                (const __attribute__((address_space(1))) void*)
                    &A[(size_t)(rowBlock + g * 8 + lrow) * D_MODEL + gchunk * 8],
                (__attribute__((address_space(3))) void*)&As[0][g * 512], 16, 0, 0);
            __builtin_amdgcn_global_load_lds(
                (const __attribute__((address_space(1))) void*)
                    &Bt[(size_t)(colBlock + g * 8 + lrow) * D_MODEL + gchunk * 8],
                (__attribute__((address_space(3))) void*)&Bs[0][g * 512], 16, 0, 0);
        }
    }

    for (int i = 0; i < 16; ++i) {             // K = 16 x 64
        __syncthreads();                       // tile i visible; buf^1 readers done
        const int buf = i & 1;
        if (i < 15) {                          // tile i+1 in flight during compute
            const int k1 = (i + 1) * 64;
#pragma unroll
            for (int n = 0; n < 4; ++n) {
                const int g = w * 4 + n;
                __builtin_amdgcn_global_load_lds(
                    (const __attribute__((address_space(1))) void*)
                        &A[(size_t)(rowBlock + g * 8 + lrow) * D_MODEL + k1 + gchunk * 8],
                    (__attribute__((address_space(3))) void*)&As[buf ^ 1][g * 512], 16, 0, 0);
                __builtin_amdgcn_global_load_lds(
                    (const __attribute__((address_space(1))) void*)
                        &Bt[(size_t)(colBlock + g * 8 + lrow) * D_MODEL + k1 + gchunk * 8],
                    (__attribute__((address_space(3))) void*)&Bs[buf ^ 1][g * 512], 16, 0, 0);
            }
        }
        const unsigned short* Ma = swp ? &Bs[buf][0] : &As[buf][0];
        const unsigned short* Mb = swp ? &As[buf][0] : &Bs[buf][0];
#pragma unroll
        for (int kc = 0; kc < 2; ++kc) {
            bvec8 af[4], bfr[4];
#pragma unroll
            for (int ii = 0; ii < 4; ++ii) {
                int r = rba + ii * 16 + l16;
                af[ii] = *(const bvec8*)&Ma[r * 64 + (((kc * 4 + quad) ^ (l16 & 7)) * 8)];
            }
#pragma unroll
            for (int j = 0; j < 4; ++j) {
                int r = rbb + j * 16 + l16;
                bfr[j] = *(const bvec8*)&Mb[r * 64 + (((kc * 4 + quad) ^ (l16 & 7)) * 8)];
            }
#pragma unroll
            for (int ii = 0; ii < 4; ++ii)
#pragma unroll
                for (int j = 0; j < 4; ++j)
                    acc[ii][j] = __builtin_amdgcn_mfma_f32_16x16x32_bf16(
                        af[ii], bfr[j], acc[ii][j], 0, 0, 0);
        }
    }

    if (mode == 0) {
        if (swp) {
            // acc[ii][j]: ii = N-frag (weight cols), j = M-frag (x rows);
            // lane: l16 = x-row, (quad, reg) = d-col. 4 regs = 4 consecutive d.
            const bool isQ = (colBlock < 1024);
#pragma unroll
            for (int ii = 0; ii < 4; ++ii) {
#pragma unroll
                for (int j = 0; j < 4; ++j) {
                    const int ncb = colBlock + wc * 64 + ii * 16 + quad * 4;
                    const int nn = ncb & 1023;
                    const int h = nn >> 6, d0 = nn & 63;
                    const float4 bv4 = *(const float4*)&bias[ncb];
                    const int mrow = rowBlock + wr * 64 + j * 16 + l16;
                    const int b = mrow >> 11, s = mrow & (SEQ - 1);
                    ushort4 pv;
                    if (isQ) {
                        pv.x = f2bf((acc[ii][j][0] + bv4.x) * qscale);
                        pv.y = f2bf((acc[ii][j][1] + bv4.y) * qscale);
                        pv.z = f2bf((acc[ii][j][2] + bv4.z) * qscale);
                        pv.w = f2bf((acc[ii][j][3] + bv4.w) * qscale);
                        *(ushort4*)&oq[(((size_t)(b * NHEADS + h) * SEQ + s) * DK) + d0] = pv;
                    } else {
                        pv.x = f2bf(acc[ii][j][0] + bv4.x);
                        pv.y = f2bf(acc[ii][j][1] + bv4.y);
                        pv.z = f2bf(acc[ii][j][2] + bv4.z);
                        pv.w = f2bf(acc[ii][j][3] + bv4.w);
                        *(ushort4*)&ok[(((size_t)(b * NHEADS + h) * SEQ + s) * DK) + d0] = pv;
                    }
                }
            }
        } else {
            // V block: original order; 4 regs = 4 consecutive s -> V^T pack
#pragma unroll
            for (int i = 0; i < 4; ++i) {
#pragma unroll
                for (int j = 0; j < 4; ++j) {
                    const int ncol = colBlock + wc * 64 + j * 16 + l16;
                    const int nn = ncol & 1023;
                    const int h = nn >> 6, d = nn & 63;
                    const float bv = bias[ncol];
                    const int mrow0 = rowBlock + wr * 64 + i * 16 + quad * 4;
                    const int b = mrow0 >> 11, s0 = mrow0 & (SEQ - 1);
                    ushort4 pv;
                    pv.x = f2bf(acc[i][j][0] + bv);
                    pv.y = f2bf(acc[i][j][1] + bv);
                    pv.z = f2bf(acc[i][j][2] + bv);
                    pv.w = f2bf(acc[i][j][3] + bv);
                    *(ushort4*)&ov[(((size_t)(b * NHEADS + h) * DK + d) * SEQ) + s0] = pv;
                }
            }
        }
    } else {
#pragma unroll
        for (int i = 0; i < 4; ++i) {
#pragma unroll
            for (int j = 0; j < 4; ++j) {
                int ncol = colBlock + wc * 64 + j * 16 + l16;
                float bv = bias[ncol];
#pragma unroll
                for (int r = 0; r < 4; ++r) {
                    int mrow = rowBlock + wr * 64 + i * 16 + quad * 4 + r;
                    of[(size_t)mrow * D_MODEL + ncol] = acc[i][j][r] + bv;
                }
            }
        }
    }
}

// ---------------- MFMA flash attention vA (32x32x16, balanced split-K) -----
__global__ __launch_bounds__(256, 4)
void attn_mfmaA(const unsigned short* __restrict__ Q,   // (B,H,S,Dk) bf16, scaled
                const unsigned short* __restrict__ K,   // (B,H,S,Dk) bf16
                const unsigned short* __restrict__ Vt,  // (B,H,Dk,S) bf16
                unsigned short* __restrict__ O,         // (B,S,H*Dk) bf16
                unsigned short* __restrict__ Opart,     // [16][64][128][64] bf16
                float* __restrict__ Lpart) {            // [16][64][128] fp32
    __shared__ __align__(16) unsigned short Ksm[2][64 * 64];  // [key][dk] swizzled
    __shared__ __align__(16) unsigned short Vsm[2][64 * 64];  // [d][key] swizzled
    __shared__ float Lsh[4][32];

    const int tid  = threadIdx.x;
    const int lane = tid & 63;
    const int wq   = tid >> 6;
    const int hf   = lane >> 5;            // half-wave
    const int l32  = lane & 31;

    // XCD swizzle: logical f -> (bx, hh, b); XCD gets contiguous head-groups
    unsigned f = (blockIdx.z * 16 + blockIdx.y) * 24 + blockIdx.x;
    f = (f & 7) * 192 + (f >> 3);          // 1536/8 = 192
    const int bx = f % 24;
    const int hh = (f / 24) & 15;
    const int b  = f / 384;
    const int hb = b * NHEADS + hh;

    // work decode (heavy-first order; mode 2 = full, 0/1 = half)
    static const int qt_tbl[24] = {15,15,7,14,14,6,13,13,12,12,5,11,
                                   11,10,10,4,9,9,8,8,3,2,1,0};
    static const int md_tbl[24] = {0,1,2,0,1,2,0,1,0,1,2,0,
                                   1,0,1,2,0,1,0,1,2,2,2,2};
    const int qt = qt_tbl[bx];
    const int md = md_tbl[bx];
    const bool part = (md < 2);
    const int kt0 = (md == 1) ? qt + 1 : 0;
    const int kt1 = (md == 0) ? qt + 1 : 2 * qt + 2;
    const int slot = part ? ((qt - 8) * 2 + md) : 0;

    const size_t bhq = ((size_t)hb) * SEQ * DK;
    const unsigned short* Qb = Q + bhq;
    const unsigned short* Kb = K + bhq;
    const unsigned short* Vb = Vt + bhq;   // (Dk, S)

    const int q0 = qt * 128 + wq * 32;     // wave's first q row (global)

    // Q B-frags (32x32x16): B[k=dk=(hf*8+j)+kc*16][n=q=l32], kept in regs
    bvec8 qf[4];
#pragma unroll
    for (int kc = 0; kc < 4; ++kc)
        qf[kc] = *(const bvec8*)&Qb[(q0 + l32) * DK + kc * 16 + hf * 8];

    // glds staging: thread t owns 16B chunks t and t+256 of each 64x64 tile.
    // chunk c = row*8 + slot; slot holds global chunk slot^(row&7).
    const int r1 = tid >> 3;               // 0..31 (second row = r1+32, same &7)
    const int lcs = (tid & 7) ^ (r1 & 7);  // pre-swizzled global chunk index

#define ATTN_STAGE(KT, NB) do {                                               \
    const unsigned short* kg_ = Kb + ((KT) * 64 + r1) * DK + lcs * 8;         \
    const unsigned short* vg_ = Vb + (size_t)r1 * SEQ + (KT) * 64 + lcs * 8;  \
    __builtin_amdgcn_global_load_lds(                                         \
        (const __attribute__((address_space(1))) void*)kg_,                   \
        (__attribute__((address_space(3))) void*)&Ksm[NB][wq * 512], 16, 0, 0); \
    __builtin_amdgcn_global_load_lds(                                         \
        (const __attribute__((address_space(1))) void*)(kg_ + 32 * DK),       \
        (__attribute__((address_space(3))) void*)&Ksm[NB][2048 + wq * 512], 16, 0, 0); \
    __builtin_amdgcn_global_load_lds(                                         \
        (const __attribute__((address_space(1))) void*)vg_,                   \
        (__attribute__((address_space(3))) void*)&Vsm[NB][wq * 512], 16, 0, 0); \
    __builtin_amdgcn_global_load_lds(                                         \
        (const __attribute__((address_space(1))) void*)(vg_ + 32 * SEQ),      \
        (__attribute__((address_space(3))) void*)&Vsm[NB][2048 + wq * 512], 16, 0, 0); \
} while (0)

    const int ktact = 2 * qt + (wq >> 1);  // this wave's diagonal tile
    const int mofs  = (wq & 1) << 5;       // key offset for diagonal masking

    ATTN_STAGE(kt0, 0);                    // preload tile kt0 into buf 0

    fvec16 acc0 = {};                      // O[q=(r&3)+8*(r>>2)+4*hf][d=l32]
    fvec16 acc1 = {};                      // same, d=32+l32
    float lp = 0.f;                        // partial l for q=l32

    for (int kt = kt0; kt < kt1; ++kt) {
        __syncthreads();                   // drains vmcnt: tile kt visible;
                                           // buf^1 readers done (prev iter)
        const int buf = (kt - kt0) & 1;
        if (kt + 1 < kt1)                  // next tile in flight during compute
            ATTN_STAGE(kt + 1, buf ^ 1);
        if (kt <= ktact) {                 // wave-uniform: skip fully-masked tiles
            const unsigned short* Kbuf = &Ksm[buf][0];
            const unsigned short* Vbuf = &Vsm[buf][0];

            fvec16 s0 = {}, s1 = {};
            __builtin_amdgcn_s_setprio(1);     // T5: favor MFMA-issuing wave
#pragma unroll
            for (int kc = 0; kc < 4; ++kc) {
                const int ch = (((kc * 2 + hf) ^ (l32 & 7)) * 8);
                bvec8 a0 = *(const bvec8*)&Kbuf[l32 * 64 + ch];
                bvec8 a1 = *(const bvec8*)&Kbuf[(32 + l32) * 64 + ch];
                s0 = __builtin_amdgcn_mfma_f32_32x32x16_bf16(a0, qf[kc], s0, 0, 0, 0);
                s1 = __builtin_amdgcn_mfma_f32_32x32x16_bf16(a1, qf[kc], s1, 0, 0, 0);
            }
            __builtin_amdgcn_s_setprio(0);

            if (kt == ktact) {             // diagonal tile: mask key > q
#pragma unroll
                for (int r = 0; r < 16; ++r) {
                    const int key0 = (r & 3) + 8 * (r >> 2) + 4 * hf - mofs;
                    if (key0 > l32)      s0[r] = -__builtin_inff();
                    if (key0 + 32 > l32) s1[r] = -__builtin_inff();
                }
            }

            unsigned pk[16];
#pragma unroll
            for (int m = 0; m < 8; ++m) {
                float p0 = fast_exp2(s0[2 * m]);
                float p1 = fast_exp2(s0[2 * m + 1]);
                float p2 = fast_exp2(s1[2 * m]);
                float p3 = fast_exp2(s1[2 * m + 1]);
                lp += (p0 + p1) + (p2 + p3);
                pk[m]     = pack_bf16x2(p0, p1);
                pk[8 + m] = pack_bf16x2(p2, p3);
            }

            __builtin_amdgcn_s_setprio(1);     // T5: PV MFMA cluster
#pragma unroll
            for (int kc16 = 0; kc16 < 4; ++kc16) {
                const int b0 = (kc16 >> 1) * 8 + (kc16 & 1) * 4;
                union { unsigned u[4]; bvec8 v; } afu;
#if __has_builtin(__builtin_amdgcn_permlane32_swap)
                {
                    auto r02 = __builtin_amdgcn_permlane32_swap(
                        pk[b0 + 0], pk[b0 + 2], false, false);
                    auto r13 = __builtin_amdgcn_permlane32_swap(
                        pk[b0 + 1], pk[b0 + 3], false, false);
                    unsigned o02[2], o13[2];
                    __builtin_memcpy(o02, &r02, 8);
                    __builtin_memcpy(o13, &r13, 8);
                    afu.u[0] = o02[0]; afu.u[2] = o02[1];
                    afu.u[1] = o13[0]; afu.u[3] = o13[1];
                }
#else
                {
                    unsigned sw0 = __shfl_xor(pk[b0 + 0], 32);
                    unsigned sw1 = __shfl_xor(pk[b0 + 1], 32);
                    unsigned sw2 = __shfl_xor(pk[b0 + 2], 32);
                    unsigned sw3 = __shfl_xor(pk[b0 + 3], 32);
                    afu.u[0] = hf ? sw2 : pk[b0 + 0];
                    afu.u[1] = hf ? sw3 : pk[b0 + 1];
                    afu.u[2] = hf ? pk[b0 + 2] : sw0;
                    afu.u[3] = hf ? pk[b0 + 3] : sw1;
                }
#endif
                const int ch = (((kc16 * 2 + hf) ^ (l32 & 7)) * 8);
                bvec8 bv0 = *(const bvec8*)&Vbuf[l32 * 64 + ch];
                bvec8 bv1 = *(const bvec8*)&Vbuf[(32 + l32) * 64 + ch];
                acc0 = __builtin_amdgcn_mfma_f32_32x32x16_bf16(afu.v, bv0, acc0, 0, 0, 0);
                acc1 = __builtin_amdgcn_mfma_f32_32x32x16_bf16(afu.v, bv1, acc1, 0, 0, 0);
            }
            __builtin_amdgcn_s_setprio(0);
        }
    }
#undef ATTN_STAGE

    const float l = lp + __shfl_xor(lp, 32);   // l(q=l32), replicated per half

    if (part) {
        if (lane < 32)
            Lpart[((size_t)slot * 64 + hb) * 128 + wq * 32 + l32] = l;
        unsigned short* Od = Opart + (((size_t)slot * 64 + hb) * 128 + wq * 32) * 64;
#pragma unroll
        for (int g = 0; g < 4; ++g)
#pragma unroll
            for (int rr = 0; rr < 4; ++rr) {
                const int reg = g * 4 + rr;
                const int qrl = g * 8 + 4 * hf + rr;
                Od[(size_t)qrl * 64 + l32]      = f2bf(acc0[reg]);
                Od[(size_t)qrl * 64 + 32 + l32] = f2bf(acc1[reg]);
            }
    } else {
        if (lane < 32) Lsh[wq][l32] = l;   // same-wave LDS dep (lgkmcnt)
#pragma unroll
        for (int g = 0; g < 4; ++g) {
            float4 lv = *(const float4*)&Lsh[wq][g * 8 + 4 * hf];
#pragma unroll
            for (int rr = 0; rr < 4; ++rr) {
                const int reg = g * 4 + rr;
                const int qrow = q0 + g * 8 + 4 * hf + rr;
                const float inv = 1.f / ((const float*)&lv)[rr];
                unsigned short* dst = O + (size_t)(b * SEQ + qrow) * D_MODEL + hh * DK + l32;
                dst[0]  = f2bf(acc0[reg] * inv);
                dst[32] = f2bf(acc1[reg] * inv);
            }
        }
    }
}

// combine the two key-chunks for qt in [8,16): O = (Oa+Ob)/(la+lb) -> bf16
__global__ void attn_combine_k(const unsigned short* __restrict__ Opart,
                               const float* __restrict__ Lpart,
                               unsigned short* __restrict__ O) {
    const int qt = 8 + blockIdx.x;
    const int h = blockIdx.y, b = blockIdx.z;
    const int hb = b * NHEADS + h;
    const int s0 = (qt - 8) * 2;
    const unsigned short* A  = Opart + ((size_t)(s0)*64 + hb) * 128 * 64;
    const unsigned short* Bp = Opart + ((size_t)(s0 + 1) * 64 + hb) * 128 * 64;
    const float* LA = Lpart + ((size_t)(s0)*64 + hb) * 128;
    const float* LB = Lpart + ((size_t)(s0 + 1) * 64 + hb) * 128;
    for (int e4 = threadIdx.x; e4 < 2048; e4 += 256) {
        const int qr = e4 >> 4, d4 = (e4 & 15) * 4;
        const float inv = 1.f / (LA[qr] + LB[qr]);
        ushort4 a = *(const ushort4*)&A[(size_t)qr * 64 + d4];
        ushort4 p = *(const ushort4*)&Bp[(size_t)qr * 64 + d4];
        ushort4 o;
        o.x = f2bf((bf2f(a.x) + bf2f(p.x)) * inv);
        o.y = f2bf((bf2f(a.y) + bf2f(p.y)) * inv);
        o.z = f2bf((bf2f(a.z) + bf2f(p.z)) * inv);
        o.w = f2bf((bf2f(a.w) + bf2f(p.w)) * inv);
        *(ushort4*)&O[(size_t)(b * SEQ + qt * 128 + qr) * D_MODEL + h * DK + d4] = o;
    }
}

// ---------------- launch ----------------

extern "C" void kernel_launch(void* const* d_in, const int* in_sizes, int n_in,
                              void* d_out, int out_size, void* d_ws, size_t ws_size,
                              hipStream_t stream) {
    const float* x  = (const float*)d_in[0];
    const float* wq = (const float*)d_in[1];
    const float* bq = (const float*)d_in[2];
    const float* wk = (const float*)d_in[3];
    const float* bk = (const float*)d_in[4];
    const float* wv = (const float*)d_in[5];
    const float* bv = (const float*)d_in[6];
    const float* wo = (const float*)d_in[7];
    const float* bo = (const float*)d_in[8];
    float* out = (float*)d_out;

    char* ws = (char*)d_ws;
    const size_t MB = 1u << 20;
    unsigned short* xb    = (unsigned short*)(ws);            // 16 MB  x bf16
    unsigned short* wqkvt = (unsigned short*)(ws + 16 * MB);  //  6 MB  [Wq;Wk;Wv]^T
    unsigned short* wot   = (unsigned short*)(ws + 22 * MB);  //  2 MB (live thru out-proj)
    unsigned short* qb    = (unsigned short*)(ws + 24 * MB);  // 16 MB each
    unsigned short* kb    = (unsigned short*)(ws + 40 * MB);
    unsigned short* vtb   = (unsigned short*)(ws + 56 * MB);  // V^T (B,H,Dk,S)
    unsigned short* ab    = (unsigned short*)(ws + 72 * MB);  // attn out, ends 88 MB
    float* cbias = (float*)(ws + 72 * MB);  // 12 KB, consumed by QKV GEMM
    // split-K partials overlay xb/wqkvt (dead after the QKV GEMM):
    unsigned short* Opart = (unsigned short*)(ws);  // 16 MB [16][64][128][64] bf16
    float* Lpart = (float*)(ws + 16 * MB);          // 512 KB [16][64][128] fp32

    // merged prep: convert (8192 blocks) | transpose (4096) | cbias (1)
    prep_all_k<<<12289, 256, 0, stream>>>(x, wq, wk, wv, wo, bq, bk, bv,
                                          xb, wqkvt, wot, cbias);

    // Q pre-scale folds softmax's 1/sqrt(Dk) AND log2(e) for exp2-domain softmax
    const float QSCALE = 0.125f * 1.44269504088896340736f;

    // fused QKV projection: N = 3072
    gemm_glds<<<dim3(3072 / 128, MROWS / 128), 256, 0, stream>>>(
        xb, wqkvt, cbias, qb, kb, vtb, nullptr, QSCALE, 0);

    attn_mfmaA<<<dim3(24, NHEADS, BATCH), 256, 0, stream>>>(
        qb, kb, vtb, ab, Opart, Lpart);
    attn_combine_k<<<dim3(8, NHEADS, BATCH), 256, 0, stream>>>(Opart, Lpart, ab);

    // out projection: fp32 output + bias
    gemm_glds<<<dim3(D_MODEL / 128, MROWS / 128), 256, 0, stream>>>(
        ab, wot, bo, nullptr, nullptr, nullptr, out, 1.0f, 1);
}